// Round 6
// baseline (311.794 us; speedup 1.0000x reference)
//
#include <hip/hip_runtime.h>

// GwcVolume: group-wise correlation cost volume.
// left/right: [B, C, H, W] fp32, C = G*CPG (320 = 40*8)
// out: [B, G, D, H, W] fp32
// out[b,g,d,h,w] = (w>=d) ? (1/CPG) * sum_ch L[b,g,ch,h,w]*R[b,g,ch,h,w-d] : 0
//
// Round 6: occupancy push via bf16-packed R.
//  - R staged in LDS as packed bf16 (RNE): 8 ch = one 16B slot per w.
//    LDS/block 40KB -> 19.9KB  => 5 blocks/CU (was 4).
//  - Window regs packed bf16 (16 VGPR, was 32); unpack at use = 1 bitop/elem
//    (v<<16 / v&0xffff0000 are exact bf16->f32). L stays exact f32.
//  - __launch_bounds__(320,7): cap 72 VGPR -> 7 waves/SIMD => 25 waves/CU
//    (was 20). R4/R5 evidence: kernel is latency-bound, time ~ 1/waves.
//  - RVEC: ONE ds_read_b128 per d-step (was 2) -> LDS traffic halved.
//  - Swizzle for 16B slots: slot' = s ^ ((s>>3)&7), bijective per 8-group
//    (312 = 39*8); worst case 2-way conflict (free, m136).

typedef float f32x4 __attribute__((ext_vector_type(4)));
typedef unsigned int u32;
typedef u32 u32x4 __attribute__((ext_vector_type(4)));

#define BB   2
#define GG   40
#define CPG  8
#define HH   96
#define WW   312
#define HW   (HH * WW)
#define ROWS 4              // h-rows per band
#define W4N  (WW / 4)       // 78 w-groups per row
#define ACT  (ROWS * W4N)   // 312 active threads
#define NTH  320            // 5 waves
#define SCALE (1.0f / CPG)

// pack two f32 -> (bf16_rne(a) | bf16_rne(b)<<16)
__device__ __forceinline__ u32 pkbf(float a, float b) {
    u32 ua = __builtin_bit_cast(u32, a);
    u32 ub = __builtin_bit_cast(u32, b);
    ua += 0x7fffu + ((ua >> 16) & 1u);
    ub += 0x7fffu + ((ub >> 16) & 1u);
    return (ua >> 16) | (ub & 0xffff0000u);
}
__device__ __forceinline__ float blo(u32 v) { return __builtin_bit_cast(float, v << 16); }
__device__ __forceinline__ float bhi(u32 v) { return __builtin_bit_cast(float, v & 0xffff0000u); }

__global__ __launch_bounds__(NTH, 7) void gwc_volume_kernel(
    const float* __restrict__ left,
    const float* __restrict__ right,
    float* __restrict__ out,
    int D)
{
    // one 16B slot per (r,w): 8 bf16 channels. 4*312*16 = 19968 B.
    __shared__ __align__(16) u32x4 s4[ROWS * WW];

    const int t    = threadIdx.x;
    const int bid  = blockIdx.x;             // = bg*(HH/ROWS) + hblk
    const int hblk = bid % (HH / ROWS);
    const int bg   = bid / (HH / ROWS);
    const int h0   = hblk * ROWS;

    const bool active = (t < ACT);
    const int  tt = active ? t : 0;
    const int  r  = tt / W4N;                // h-row within band
    const int  w4 = tt - r * W4N;
    const int  w0 = 4 * w4;

    const size_t base   = (size_t)bg * CPG * HW + (size_t)h0 * WW;
    const size_t rowoff = base + (size_t)r * WW + w0;

    float LJ[4][8];          // L operands, exact f32, pre-scaled by 1/CPG

    if (active) {
        // issue all 16 loads back-to-back (full MLP)
        f32x4 R[8], L[8];
        #pragma unroll
        for (int c = 0; c < CPG; ++c)
            R[c] = *(const f32x4*)(right + rowoff + (size_t)c * HW);
        #pragma unroll
        for (int c = 0; c < CPG; ++c)
            L[c] = *(const f32x4*)(left + rowoff + (size_t)c * HW);

        // pack R -> bf16 slots, swizzled ds_write_b128 (4 per thread)
        u32x4* srow = s4 + r * WW;
        #pragma unroll
        for (int i = 0; i < 4; ++i) {
            const int s  = w0 + i;
            const int sl = s ^ ((s >> 3) & 7);
            u32x4 v;
            v.x = pkbf(R[0][i], R[1][i]);
            v.y = pkbf(R[2][i], R[3][i]);
            v.z = pkbf(R[4][i], R[5][i]);
            v.w = pkbf(R[6][i], R[7][i]);
            srow[sl] = v;
        }

        #pragma unroll
        for (int c = 0; c < CPG; ++c) {
            LJ[0][c] = L[c].x * SCALE;
            LJ[1][c] = L[c].y * SCALE;
            LJ[2][c] = L[c].z * SCALE;
            LJ[3][c] = L[c].w * SCALE;
        }
    } else {
        #pragma unroll
        for (int j = 0; j < 4; ++j)
            #pragma unroll
            for (int c = 0; c < CPG; ++c)
                LJ[j][c] = 0.0f;
    }
    __syncthreads();

    const u32x4* f4row = s4 + r * WW;

    #define RVEC(x, A) do {                          \
        int xi_ = (x) < 0 ? 0 : (x);                 \
        A = f4row[xi_ ^ ((xi_ >> 3) & 7)];           \
    } while (0)

    #define DOT8(j, A) ( blo(A.x)*LJ[j][0] + bhi(A.x)*LJ[j][1]   \
                       + blo(A.y)*LJ[j][2] + bhi(A.y)*LJ[j][3]   \
                       + blo(A.z)*LJ[j][4] + bhi(A.z)*LJ[j][5]   \
                       + blo(A.w)*LJ[j][6] + bhi(A.w)*LJ[j][7] )

    #define STEP(A_0, A_1, A_2, A_3) do {                  \
        f32x4 st_;                                         \
        st_.x = (x0     >= 0) ? DOT8(0, A_0) : 0.0f;       \
        st_.y = (x0 + 1 >= 0) ? DOT8(1, A_1) : 0.0f;       \
        st_.z = (x0 + 2 >= 0) ? DOT8(2, A_2) : 0.0f;       \
        st_.w = (x0 + 3 >= 0) ? DOT8(3, A_3) : 0.0f;       \
        if (active) *(f32x4*)op = st_;                     \
        op += HW;                                          \
    } while (0)

    // init window: W_j = R[w0+j] (all indices >= 0)
    u32x4 A0, A1, A2, A3;
    RVEC(w0 + 0, A0);
    RVEC(w0 + 1, A1);
    RVEC(w0 + 2, A2);
    RVEC(w0 + 3, A3);

    float* op = out + (size_t)bg * D * HW + (size_t)(h0 + r) * WW + w0;
    int x0 = w0;                       // = w0 - d

    const int nq = D >> 2;
    for (int q = 0; q < nq; ++q) {
        STEP(A0, A1, A2, A3);  RVEC(x0 - 1, A3);  x0 -= 1;
        STEP(A3, A0, A1, A2);  RVEC(x0 - 1, A2);  x0 -= 1;
        STEP(A2, A3, A0, A1);  RVEC(x0 - 1, A1);  x0 -= 1;
        STEP(A1, A2, A3, A0);  RVEC(x0 - 1, A0);  x0 -= 1;
    }

    // remainder for D % 4 != 0 (dead for D=48, kept for safety)
    for (int d = nq * 4; d < D; ++d) {
        const int xb = w0 - d;
        u32x4 Xa;
        f32x4 st_;
        RVEC(xb + 0, Xa); st_.x = (xb     >= 0) ? DOT8(0, Xa) : 0.0f;
        RVEC(xb + 1, Xa); st_.y = (xb + 1 >= 0) ? DOT8(1, Xa) : 0.0f;
        RVEC(xb + 2, Xa); st_.z = (xb + 2 >= 0) ? DOT8(2, Xa) : 0.0f;
        RVEC(xb + 3, Xa); st_.w = (xb + 3 >= 0) ? DOT8(3, Xa) : 0.0f;
        if (active) *(f32x4*)op = st_;
        op += HW;
    }

    #undef RVEC
    #undef DOT8
    #undef STEP
}

extern "C" void kernel_launch(void* const* d_in, const int* in_sizes, int n_in,
                              void* d_out, int out_size, void* d_ws, size_t ws_size,
                              hipStream_t stream) {
    const float* left  = (const float*)d_in[0];
    const float* right = (const float*)d_in[1];
    float* out = (float*)d_out;

    // max_disp lives in device memory (d_in[2]); derive D from out_size on host.
    const int D = out_size / (BB * GG * HH * WW);   // = 48

    dim3 grid(BB * GG * (HH / ROWS));   // 1920 blocks, one per (b,g,4-row band)
    dim3 block(NTH);                    // 5 waves; 312 active threads
    hipLaunchKernelGGL(gwc_volume_kernel, grid, block, 0, stream,
                       left, right, out, D);
}

// Round 7
// 195.152 us; speedup vs baseline: 1.5977x; 1.5977x over previous
//
#include <hip/hip_runtime.h>

// GwcVolume: group-wise correlation cost volume.
// left/right: [B, C, H, W] fp32, C = G*CPG (320 = 40*8)
// out: [B, G, D, H, W] fp32
// out[b,g,d,h,w] = (w>=d) ? (1/CPG) * sum_ch L[b,g,ch,h,w]*R[b,g,ch,h,w-d] : 0
//
// Round 7 = R6's bf16-LDS design with the spill fixed + finer wave granularity.
//  - R staged in LDS as packed bf16 (RNE): 8 ch = one 16B slot per w.
//    RVEC = ONE ds_read_b128 per d-step. Swizzle slot' = s ^ ((s>>3)&7)
//    (8-lane groups at x-stride 4 cover all 8 bank-groups -> conflict-free;
//    R6's 2M conflicts were a spill artifact).
//  - Window regs packed bf16 (u32x4 x4 = 16 VGPR); L stays exact f32 (32).
//    Live set ~70.
//  - Block = 256 threads (4 waves), ROWS=3 (234 active): wave granularity 4.
//    __launch_bounds__(256,6): VGPR cap 85 >> live set -> NO spill (R6 lesson:
//    cap 72 vs live ~90 -> scratch catastrophe). LDS 14976B/block.
//    VGPR<=85 -> 6 blocks/CU = 24 waves (+20% vs R5); LDS never binds.
//  - d-loop: register sliding window, unrolled x4 with rotation; f32x4 stores.

typedef float f32x4 __attribute__((ext_vector_type(4)));
typedef unsigned int u32;
typedef u32 u32x4 __attribute__((ext_vector_type(4)));

#define BB   2
#define GG   40
#define CPG  8
#define HH   96
#define WW   312
#define HW   (HH * WW)
#define ROWS 3              // h-rows per band
#define W4N  (WW / 4)       // 78 w-groups per row
#define ACT  (ROWS * W4N)   // 234 active threads
#define NTH  256            // 4 waves
#define HBLKS (HH / ROWS)   // 32 bands per (b,g)
#define SCALE (1.0f / CPG)

// pack two f32 -> (bf16_rne(a) | bf16_rne(b)<<16)
__device__ __forceinline__ u32 pkbf(float a, float b) {
    u32 ua = __builtin_bit_cast(u32, a);
    u32 ub = __builtin_bit_cast(u32, b);
    ua += 0x7fffu + ((ua >> 16) & 1u);
    ub += 0x7fffu + ((ub >> 16) & 1u);
    return (ua >> 16) | (ub & 0xffff0000u);
}
__device__ __forceinline__ float blo(u32 v) { return __builtin_bit_cast(float, v << 16); }
__device__ __forceinline__ float bhi(u32 v) { return __builtin_bit_cast(float, v & 0xffff0000u); }

__global__ __launch_bounds__(NTH, 6) void gwc_volume_kernel(
    const float* __restrict__ left,
    const float* __restrict__ right,
    float* __restrict__ out,
    int D)
{
    // one 16B slot per (r,w): 8 bf16 channels. 3*312*16 = 14976 B.
    __shared__ __align__(16) u32x4 s4[ROWS * WW];

    const int t    = threadIdx.x;
    const int bid  = blockIdx.x;             // = bg*HBLKS + hblk
    const int hblk = bid % HBLKS;
    const int bg   = bid / HBLKS;
    const int h0   = hblk * ROWS;

    const bool active = (t < ACT);
    const int  tt = active ? t : 0;
    const int  r  = tt / W4N;                // h-row within band
    const int  w4 = tt - r * W4N;
    const int  w0 = 4 * w4;

    const size_t base   = (size_t)bg * CPG * HW + (size_t)h0 * WW;
    const size_t rowoff = base + (size_t)r * WW + w0;

    float LJ[4][8];          // L operands, exact f32, pre-scaled by 1/CPG

    if (active) {
        // issue all 16 loads back-to-back (full MLP)
        f32x4 R[8], L[8];
        #pragma unroll
        for (int c = 0; c < CPG; ++c)
            R[c] = *(const f32x4*)(right + rowoff + (size_t)c * HW);
        #pragma unroll
        for (int c = 0; c < CPG; ++c)
            L[c] = *(const f32x4*)(left + rowoff + (size_t)c * HW);

        // pack R -> bf16 slots, swizzled ds_write_b128 (4 per thread)
        u32x4* srow = s4 + r * WW;
        #pragma unroll
        for (int i = 0; i < 4; ++i) {
            const int s  = w0 + i;
            const int sl = s ^ ((s >> 3) & 7);
            u32x4 v;
            v.x = pkbf(R[0][i], R[1][i]);
            v.y = pkbf(R[2][i], R[3][i]);
            v.z = pkbf(R[4][i], R[5][i]);
            v.w = pkbf(R[6][i], R[7][i]);
            srow[sl] = v;
        }

        #pragma unroll
        for (int c = 0; c < CPG; ++c) {
            LJ[0][c] = L[c].x * SCALE;
            LJ[1][c] = L[c].y * SCALE;
            LJ[2][c] = L[c].z * SCALE;
            LJ[3][c] = L[c].w * SCALE;
        }
    } else {
        #pragma unroll
        for (int j = 0; j < 4; ++j)
            #pragma unroll
            for (int c = 0; c < CPG; ++c)
                LJ[j][c] = 0.0f;
    }
    __syncthreads();

    const u32x4* f4row = s4 + r * WW;

    #define RVEC(x, A) do {                          \
        int xi_ = (x) < 0 ? 0 : (x);                 \
        A = f4row[xi_ ^ ((xi_ >> 3) & 7)];           \
    } while (0)

    #define DOT8(j, A) ( blo(A.x)*LJ[j][0] + bhi(A.x)*LJ[j][1]   \
                       + blo(A.y)*LJ[j][2] + bhi(A.y)*LJ[j][3]   \
                       + blo(A.z)*LJ[j][4] + bhi(A.z)*LJ[j][5]   \
                       + blo(A.w)*LJ[j][6] + bhi(A.w)*LJ[j][7] )

    #define STEP(A_0, A_1, A_2, A_3) do {                  \
        f32x4 st_;                                         \
        st_.x = (x0     >= 0) ? DOT8(0, A_0) : 0.0f;       \
        st_.y = (x0 + 1 >= 0) ? DOT8(1, A_1) : 0.0f;       \
        st_.z = (x0 + 2 >= 0) ? DOT8(2, A_2) : 0.0f;       \
        st_.w = (x0 + 3 >= 0) ? DOT8(3, A_3) : 0.0f;       \
        if (active) *(f32x4*)op = st_;                     \
        op += HW;                                          \
    } while (0)

    // init window: W_j = R[w0+j] (all indices >= 0)
    u32x4 A0, A1, A2, A3;
    RVEC(w0 + 0, A0);
    RVEC(w0 + 1, A1);
    RVEC(w0 + 2, A2);
    RVEC(w0 + 3, A3);

    float* op = out + (size_t)bg * D * HW + (size_t)(h0 + r) * WW + w0;
    int x0 = w0;                       // = w0 - d

    const int nq = D >> 2;
    for (int q = 0; q < nq; ++q) {
        STEP(A0, A1, A2, A3);  RVEC(x0 - 1, A3);  x0 -= 1;
        STEP(A3, A0, A1, A2);  RVEC(x0 - 1, A2);  x0 -= 1;
        STEP(A2, A3, A0, A1);  RVEC(x0 - 1, A1);  x0 -= 1;
        STEP(A1, A2, A3, A0);  RVEC(x0 - 1, A0);  x0 -= 1;
    }

    // remainder for D % 4 != 0 (dead for D=48, kept for safety)
    for (int d = nq * 4; d < D; ++d) {
        const int xb = w0 - d;
        u32x4 Xa;
        f32x4 st_;
        RVEC(xb + 0, Xa); st_.x = (xb     >= 0) ? DOT8(0, Xa) : 0.0f;
        RVEC(xb + 1, Xa); st_.y = (xb + 1 >= 0) ? DOT8(1, Xa) : 0.0f;
        RVEC(xb + 2, Xa); st_.z = (xb + 2 >= 0) ? DOT8(2, Xa) : 0.0f;
        RVEC(xb + 3, Xa); st_.w = (xb + 3 >= 0) ? DOT8(3, Xa) : 0.0f;
        if (active) *(f32x4*)op = st_;
        op += HW;
    }

    #undef RVEC
    #undef DOT8
    #undef STEP
}

extern "C" void kernel_launch(void* const* d_in, const int* in_sizes, int n_in,
                              void* d_out, int out_size, void* d_ws, size_t ws_size,
                              hipStream_t stream) {
    const float* left  = (const float*)d_in[0];
    const float* right = (const float*)d_in[1];
    float* out = (float*)d_out;

    // max_disp lives in device memory (d_in[2]); derive D from out_size on host.
    const int D = out_size / (BB * GG * HH * WW);   // = 48

    dim3 grid(BB * GG * HBLKS);   // 2560 blocks, one per (b,g,3-row band)
    dim3 block(NTH);              // 4 waves; 234 active threads
    hipLaunchKernelGGL(gwc_volume_kernel, grid, block, 0, stream,
                       left, right, out, D);
}

// Round 8
// 194.703 us; speedup vs baseline: 1.6014x; 1.0023x over previous
//
#include <hip/hip_runtime.h>

// GwcVolume: group-wise correlation cost volume.
// left/right: [B, C, H, W] fp32, C = G*CPG (320 = 40*8)
// out: [B, G, D, H, W] fp32
// out[b,g,d,h,w] = (w>=d) ? (1/CPG) * sum_ch L[b,g,ch,h,w]*R[b,g,ch,h,w-d] : 0
//
// Round 8 = R7 with the staging register spike removed (R6/R7 post-mortem:
// all-16-loads-first put R[8]+L[8]+LJ = 96 regs live vs caps 72/85 -> spill).
//  - TWO-PHASE staging: load R[8] -> pack to LDS (frees 32 regs) -> load L[8]
//    -> fold into LJ. Peak live ~55, steady-state ~62.
//  - __launch_bounds__(256,6): cap 85 >> live set. min-waves only CAPS the
//    allocator; if natural VGPR <= 73 we get 7 blocks (28 waves) free.
//  - R in LDS as packed bf16 (RNE): 8 ch = one 16B slot per w; ONE
//    ds_read_b128 per d-step. Swizzle slot' = s ^ ((s>>3)&7). 14976 B/block.
//  - Window regs packed bf16 (u32x4 x4 = 16 VGPR); L exact f32, pre-scaled.
//  - Block 256 threads (4-wave granularity), ROWS=3, grid 2560.
//  - d-loop: register sliding window, unrolled x4 with rotation; f32x4 stores.

typedef float f32x4 __attribute__((ext_vector_type(4)));
typedef unsigned int u32;
typedef u32 u32x4 __attribute__((ext_vector_type(4)));

#define BB   2
#define GG   40
#define CPG  8
#define HH   96
#define WW   312
#define HW   (HH * WW)
#define ROWS 3              // h-rows per band
#define W4N  (WW / 4)       // 78 w-groups per row
#define ACT  (ROWS * W4N)   // 234 active threads
#define NTH  256            // 4 waves
#define HBLKS (HH / ROWS)   // 32 bands per (b,g)
#define SCALE (1.0f / CPG)

// pack two f32 -> (bf16_rne(a) | bf16_rne(b)<<16)
__device__ __forceinline__ u32 pkbf(float a, float b) {
    u32 ua = __builtin_bit_cast(u32, a);
    u32 ub = __builtin_bit_cast(u32, b);
    ua += 0x7fffu + ((ua >> 16) & 1u);
    ub += 0x7fffu + ((ub >> 16) & 1u);
    return (ua >> 16) | (ub & 0xffff0000u);
}
__device__ __forceinline__ float blo(u32 v) { return __builtin_bit_cast(float, v << 16); }
__device__ __forceinline__ float bhi(u32 v) { return __builtin_bit_cast(float, v & 0xffff0000u); }

__global__ __launch_bounds__(NTH, 6) void gwc_volume_kernel(
    const float* __restrict__ left,
    const float* __restrict__ right,
    float* __restrict__ out,
    int D)
{
    // one 16B slot per (r,w): 8 bf16 channels. 3*312*16 = 14976 B.
    __shared__ __align__(16) u32x4 s4[ROWS * WW];

    const int t    = threadIdx.x;
    const int bid  = blockIdx.x;             // = bg*HBLKS + hblk
    const int hblk = bid % HBLKS;
    const int bg   = bid / HBLKS;
    const int h0   = hblk * ROWS;

    const bool active = (t < ACT);
    const int  tt = active ? t : 0;
    const int  r  = tt / W4N;                // h-row within band
    const int  w4 = tt - r * W4N;
    const int  w0 = 4 * w4;

    const size_t base   = (size_t)bg * CPG * HW + (size_t)h0 * WW;
    const size_t rowoff = base + (size_t)r * WW + w0;

    float LJ[4][8];          // L operands, exact f32, pre-scaled by 1/CPG

    if (active) {
        // ---- phase 1: R -> pack -> LDS (R regs freed before L loads) ----
        {
            f32x4 R[8];
            #pragma unroll
            for (int c = 0; c < CPG; ++c)
                R[c] = *(const f32x4*)(right + rowoff + (size_t)c * HW);

            u32x4* srow = s4 + r * WW;
            #pragma unroll
            for (int i = 0; i < 4; ++i) {
                const int s  = w0 + i;
                const int sl = s ^ ((s >> 3) & 7);
                u32x4 v;
                v.x = pkbf(R[0][i], R[1][i]);
                v.y = pkbf(R[2][i], R[3][i]);
                v.z = pkbf(R[4][i], R[5][i]);
                v.w = pkbf(R[6][i], R[7][i]);
                srow[sl] = v;
            }
        }
        // ---- phase 2: L -> LJ (per-channel, low live count) ----
        #pragma unroll
        for (int c = 0; c < CPG; ++c) {
            f32x4 lv = *(const f32x4*)(left + rowoff + (size_t)c * HW);
            LJ[0][c] = lv.x * SCALE;
            LJ[1][c] = lv.y * SCALE;
            LJ[2][c] = lv.z * SCALE;
            LJ[3][c] = lv.w * SCALE;
        }
    } else {
        #pragma unroll
        for (int j = 0; j < 4; ++j)
            #pragma unroll
            for (int c = 0; c < CPG; ++c)
                LJ[j][c] = 0.0f;
    }
    __syncthreads();

    const u32x4* f4row = s4 + r * WW;

    #define RVEC(x, A) do {                          \
        int xi_ = (x) < 0 ? 0 : (x);                 \
        A = f4row[xi_ ^ ((xi_ >> 3) & 7)];           \
    } while (0)

    #define DOT8(j, A) ( blo(A.x)*LJ[j][0] + bhi(A.x)*LJ[j][1]   \
                       + blo(A.y)*LJ[j][2] + bhi(A.y)*LJ[j][3]   \
                       + blo(A.z)*LJ[j][4] + bhi(A.z)*LJ[j][5]   \
                       + blo(A.w)*LJ[j][6] + bhi(A.w)*LJ[j][7] )

    #define STEP(A_0, A_1, A_2, A_3) do {                  \
        f32x4 st_;                                         \
        st_.x = (x0     >= 0) ? DOT8(0, A_0) : 0.0f;       \
        st_.y = (x0 + 1 >= 0) ? DOT8(1, A_1) : 0.0f;       \
        st_.z = (x0 + 2 >= 0) ? DOT8(2, A_2) : 0.0f;       \
        st_.w = (x0 + 3 >= 0) ? DOT8(3, A_3) : 0.0f;       \
        if (active) *(f32x4*)op = st_;                     \
        op += HW;                                          \
    } while (0)

    // init window: W_j = R[w0+j] (all indices >= 0)
    u32x4 A0, A1, A2, A3;
    RVEC(w0 + 0, A0);
    RVEC(w0 + 1, A1);
    RVEC(w0 + 2, A2);
    RVEC(w0 + 3, A3);

    float* op = out + (size_t)bg * D * HW + (size_t)(h0 + r) * WW + w0;
    int x0 = w0;                       // = w0 - d

    const int nq = D >> 2;
    for (int q = 0; q < nq; ++q) {
        STEP(A0, A1, A2, A3);  RVEC(x0 - 1, A3);  x0 -= 1;
        STEP(A3, A0, A1, A2);  RVEC(x0 - 1, A2);  x0 -= 1;
        STEP(A2, A3, A0, A1);  RVEC(x0 - 1, A1);  x0 -= 1;
        STEP(A1, A2, A3, A0);  RVEC(x0 - 1, A0);  x0 -= 1;
    }

    // remainder for D % 4 != 0 (dead for D=48, kept for safety)
    for (int d = nq * 4; d < D; ++d) {
        const int xb = w0 - d;
        u32x4 Xa;
        f32x4 st_;
        RVEC(xb + 0, Xa); st_.x = (xb     >= 0) ? DOT8(0, Xa) : 0.0f;
        RVEC(xb + 1, Xa); st_.y = (xb + 1 >= 0) ? DOT8(1, Xa) : 0.0f;
        RVEC(xb + 2, Xa); st_.z = (xb + 2 >= 0) ? DOT8(2, Xa) : 0.0f;
        RVEC(xb + 3, Xa); st_.w = (xb + 3 >= 0) ? DOT8(3, Xa) : 0.0f;
        if (active) *(f32x4*)op = st_;
        op += HW;
    }

    #undef RVEC
    #undef DOT8
    #undef STEP
}

extern "C" void kernel_launch(void* const* d_in, const int* in_sizes, int n_in,
                              void* d_out, int out_size, void* d_ws, size_t ws_size,
                              hipStream_t stream) {
    const float* left  = (const float*)d_in[0];
    const float* right = (const float*)d_in[1];
    float* out = (float*)d_out;

    // max_disp lives in device memory (d_in[2]); derive D from out_size on host.
    const int D = out_size / (BB * GG * HH * WW);   // = 48

    dim3 grid(BB * GG * HBLKS);   // 2560 blocks, one per (b,g,3-row band)
    dim3 block(NTH);              // 4 waves; 234 active threads
    hipLaunchKernelGGL(gwc_volume_kernel, grid, block, 0, stream,
                       left, right, out, D);
}

// Round 9
// 147.351 us; speedup vs baseline: 2.1160x; 1.3214x over previous
//
#include <hip/hip_runtime.h>

// GwcVolume: group-wise correlation cost volume.
// left/right: [B, C, H, W] fp32, C = G*CPG (320 = 40*8)
// out: [B, G, D, H, W] fp32
// out[b,g,d,h,w] = (w>=d) ? (1/CPG) * sum_ch L[b,g,ch,h,w]*R[b,g,ch,h,w-d] : 0
//
// Round 9 = R8 with __launch_bounds__ REMOVED (the decisive A/B on the cap).
// History: R5 (f32 LDS, LDS-bound 4 blocks/20 waves) = 137.9us clean.
// R6/R7/R8 tried to raise occupancy with VGPR caps 72/85 -> allocator spill
// (R6: VGPR_Count=36 collapse + scratch FETCH/WRITE overshoot) -> 195-312us.
// The 24-wave config has never run WITHOUT a cap. This round: natural
// allocation (live set ~62-75) should land <=84 VGPR -> 6 waves/SIMD ->
// 6 blocks x 4 waves = 24 waves/CU, zero spill risk (LDS 6x14976B=90K).
//  - R staged in LDS as packed bf16 (RNE): 8 ch = one 16B slot per w; ONE
//    ds_read_b128 per d-step. Swizzle slot' = s ^ ((s>>3)&7). 14976 B/block.
//  - Two-phase staging (R->LDS, then L->LJ) to keep live range low.
//  - Window regs packed bf16 (u32x4 x4 = 16 VGPR); L exact f32, pre-scaled.
//  - Block 256 threads, ROWS=3 (234 active), grid 2560.
//  - d-loop: register sliding window, unrolled x4 with rotation; f32x4 stores.

typedef float f32x4 __attribute__((ext_vector_type(4)));
typedef unsigned int u32;
typedef u32 u32x4 __attribute__((ext_vector_type(4)));

#define BB   2
#define GG   40
#define CPG  8
#define HH   96
#define WW   312
#define HW   (HH * WW)
#define ROWS 3              // h-rows per band
#define W4N  (WW / 4)       // 78 w-groups per row
#define ACT  (ROWS * W4N)   // 234 active threads
#define NTH  256            // 4 waves
#define HBLKS (HH / ROWS)   // 32 bands per (b,g)
#define SCALE (1.0f / CPG)

// pack two f32 -> (bf16_rne(a) | bf16_rne(b)<<16)
__device__ __forceinline__ u32 pkbf(float a, float b) {
    u32 ua = __builtin_bit_cast(u32, a);
    u32 ub = __builtin_bit_cast(u32, b);
    ua += 0x7fffu + ((ua >> 16) & 1u);
    ub += 0x7fffu + ((ub >> 16) & 1u);
    return (ua >> 16) | (ub & 0xffff0000u);
}
__device__ __forceinline__ float blo(u32 v) { return __builtin_bit_cast(float, v << 16); }
__device__ __forceinline__ float bhi(u32 v) { return __builtin_bit_cast(float, v & 0xffff0000u); }

__global__ void gwc_volume_kernel(
    const float* __restrict__ left,
    const float* __restrict__ right,
    float* __restrict__ out,
    int D)
{
    // one 16B slot per (r,w): 8 bf16 channels. 3*312*16 = 14976 B.
    __shared__ __align__(16) u32x4 s4[ROWS * WW];

    const int t    = threadIdx.x;
    const int bid  = blockIdx.x;             // = bg*HBLKS + hblk
    const int hblk = bid % HBLKS;
    const int bg   = bid / HBLKS;
    const int h0   = hblk * ROWS;

    const bool active = (t < ACT);
    const int  tt = active ? t : 0;
    const int  r  = tt / W4N;                // h-row within band
    const int  w4 = tt - r * W4N;
    const int  w0 = 4 * w4;

    const size_t base   = (size_t)bg * CPG * HW + (size_t)h0 * WW;
    const size_t rowoff = base + (size_t)r * WW + w0;

    float LJ[4][8];          // L operands, exact f32, pre-scaled by 1/CPG

    if (active) {
        // ---- phase 1: R -> pack -> LDS ----
        {
            f32x4 R[8];
            #pragma unroll
            for (int c = 0; c < CPG; ++c)
                R[c] = *(const f32x4*)(right + rowoff + (size_t)c * HW);

            u32x4* srow = s4 + r * WW;
            #pragma unroll
            for (int i = 0; i < 4; ++i) {
                const int s  = w0 + i;
                const int sl = s ^ ((s >> 3) & 7);
                u32x4 v;
                v.x = pkbf(R[0][i], R[1][i]);
                v.y = pkbf(R[2][i], R[3][i]);
                v.z = pkbf(R[4][i], R[5][i]);
                v.w = pkbf(R[6][i], R[7][i]);
                srow[sl] = v;
            }
        }
        // ---- phase 2: L -> LJ (per-channel) ----
        #pragma unroll
        for (int c = 0; c < CPG; ++c) {
            f32x4 lv = *(const f32x4*)(left + rowoff + (size_t)c * HW);
            LJ[0][c] = lv.x * SCALE;
            LJ[1][c] = lv.y * SCALE;
            LJ[2][c] = lv.z * SCALE;
            LJ[3][c] = lv.w * SCALE;
        }
    } else {
        #pragma unroll
        for (int j = 0; j < 4; ++j)
            #pragma unroll
            for (int c = 0; c < CPG; ++c)
                LJ[j][c] = 0.0f;
    }
    __syncthreads();

    const u32x4* f4row = s4 + r * WW;

    #define RVEC(x, A) do {                          \
        int xi_ = (x) < 0 ? 0 : (x);                 \
        A = f4row[xi_ ^ ((xi_ >> 3) & 7)];           \
    } while (0)

    #define DOT8(j, A) ( blo(A.x)*LJ[j][0] + bhi(A.x)*LJ[j][1]   \
                       + blo(A.y)*LJ[j][2] + bhi(A.y)*LJ[j][3]   \
                       + blo(A.z)*LJ[j][4] + bhi(A.z)*LJ[j][5]   \
                       + blo(A.w)*LJ[j][6] + bhi(A.w)*LJ[j][7] )

    #define STEP(A_0, A_1, A_2, A_3) do {                  \
        f32x4 st_;                                         \
        st_.x = (x0     >= 0) ? DOT8(0, A_0) : 0.0f;       \
        st_.y = (x0 + 1 >= 0) ? DOT8(1, A_1) : 0.0f;       \
        st_.z = (x0 + 2 >= 0) ? DOT8(2, A_2) : 0.0f;       \
        st_.w = (x0 + 3 >= 0) ? DOT8(3, A_3) : 0.0f;       \
        if (active) *(f32x4*)op = st_;                     \
        op += HW;                                          \
    } while (0)

    // init window: W_j = R[w0+j] (all indices >= 0)
    u32x4 A0, A1, A2, A3;
    RVEC(w0 + 0, A0);
    RVEC(w0 + 1, A1);
    RVEC(w0 + 2, A2);
    RVEC(w0 + 3, A3);

    float* op = out + (size_t)bg * D * HW + (size_t)(h0 + r) * WW + w0;
    int x0 = w0;                       // = w0 - d

    const int nq = D >> 2;
    for (int q = 0; q < nq; ++q) {
        STEP(A0, A1, A2, A3);  RVEC(x0 - 1, A3);  x0 -= 1;
        STEP(A3, A0, A1, A2);  RVEC(x0 - 1, A2);  x0 -= 1;
        STEP(A2, A3, A0, A1);  RVEC(x0 - 1, A1);  x0 -= 1;
        STEP(A1, A2, A3, A0);  RVEC(x0 - 1, A0);  x0 -= 1;
    }

    // remainder for D % 4 != 0 (dead for D=48, kept for safety)
    for (int d = nq * 4; d < D; ++d) {
        const int xb = w0 - d;
        u32x4 Xa;
        f32x4 st_;
        RVEC(xb + 0, Xa); st_.x = (xb     >= 0) ? DOT8(0, Xa) : 0.0f;
        RVEC(xb + 1, Xa); st_.y = (xb + 1 >= 0) ? DOT8(1, Xa) : 0.0f;
        RVEC(xb + 2, Xa); st_.z = (xb + 2 >= 0) ? DOT8(2, Xa) : 0.0f;
        RVEC(xb + 3, Xa); st_.w = (xb + 3 >= 0) ? DOT8(3, Xa) : 0.0f;
        if (active) *(f32x4*)op = st_;
        op += HW;
    }

    #undef RVEC
    #undef DOT8
    #undef STEP
}

extern "C" void kernel_launch(void* const* d_in, const int* in_sizes, int n_in,
                              void* d_out, int out_size, void* d_ws, size_t ws_size,
                              hipStream_t stream) {
    const float* left  = (const float*)d_in[0];
    const float* right = (const float*)d_in[1];
    float* out = (float*)d_out;

    // max_disp lives in device memory (d_in[2]); derive D from out_size on host.
    const int D = out_size / (BB * GG * HH * WW);   // = 48

    dim3 grid(BB * GG * HBLKS);   // 2560 blocks, one per (b,g,3-row band)
    dim3 block(NTH);              // 4 waves; 234 active threads
    hipLaunchKernelGGL(gwc_volume_kernel, grid, block, 0, stream,
                       left, right, out, D);
}

// Round 10
// 144.745 us; speedup vs baseline: 2.1541x; 1.0180x over previous
//
#include <hip/hip_runtime.h>

// GwcVolume: group-wise correlation cost volume.
// left/right: [B, C, H, W] fp32, C = G*CPG (320 = 40*8)
// out: [B, G, D, H, W] fp32
// out[b,g,d,h,w] = (w>=d) ? (1/CPG) * sum_ch L[b,g,ch,h,w]*R[b,g,ch,h,w-d] : 0
//
// Round 10 = R9 + v_dot2_f32_bf16 (packed bf16 dot2, f32 accumulate).
// R9 post-mortem: natural VGPR ~90-110 (spilled under cap 85) -> still only
// 16-20 waves/CU; occupancy never exceeded 20 waves. This round collapses the
// register state AND the VALU:
//  - L packed bf16 too (LJ: 16 VGPR, was 32 f32); 1/CPG folded into L BEFORE
//    packing (pow2 scale = exact in bf16).
//  - DOT8 = 4 chained v_dot2_f32_bf16 (was 8 unpack + 8 FMA): ~24 VALU/STEP.
//  - d-loop live set ~50 -> natural alloc <=64-84, NO launch_bounds cap
//    (caps spill: R6/R7/R8) -> 6-8 waves/SIMD -> 24-32 waves/CU.
//  - Rest identical to R9: bf16 LDS [r][w][8ch] 16B slots, swizzle
//    s^((s>>3)&7), ONE ds_read_b128/d-step, sliding window unrolled x4,
//    f32x4 stores. Block 256 thr, ROWS=3, grid 2560.
// Accuracy: both operands bf16-RNE -> predicted absmax ~0.03 (thr 0.0653).

typedef float f32x4 __attribute__((ext_vector_type(4)));
typedef unsigned int u32;
typedef u32 u32x4 __attribute__((ext_vector_type(4)));

#define BB   2
#define GG   40
#define CPG  8
#define HH   96
#define WW   312
#define HW   (HH * WW)
#define ROWS 3              // h-rows per band
#define W4N  (WW / 4)       // 78 w-groups per row
#define ACT  (ROWS * W4N)   // 234 active threads
#define NTH  256            // 4 waves
#define HBLKS (HH / ROWS)   // 32 bands per (b,g)
#define SCALE (1.0f / CPG)

// pack two f32 -> (bf16_rne(a) | bf16_rne(b)<<16)
__device__ __forceinline__ u32 pkbf(float a, float b) {
    u32 ua = __builtin_bit_cast(u32, a);
    u32 ub = __builtin_bit_cast(u32, b);
    ua += 0x7fffu + ((ua >> 16) & 1u);
    ub += 0x7fffu + ((ub >> 16) & 1u);
    return (ua >> 16) | (ub & 0xffff0000u);
}

// D = a.lo*b.lo + a.hi*b.hi + c   (packed bf16 pair dot, f32 accum)
__device__ __forceinline__ float dot2bf(u32 a, u32 b, float c) {
    float d;
    asm("v_dot2_f32_bf16 %0, %1, %2, %3" : "=v"(d) : "v"(a), "v"(b), "v"(c));
    return d;
}

// 8-channel dot: a,b = 4 packed pairs each
__device__ __forceinline__ float dot8bf(u32x4 a, u32x4 b) {
    float acc = dot2bf(a.x, b.x, 0.0f);
    acc = dot2bf(a.y, b.y, acc);
    acc = dot2bf(a.z, b.z, acc);
    acc = dot2bf(a.w, b.w, acc);
    return acc;
}

__global__ void gwc_volume_kernel(
    const float* __restrict__ left,
    const float* __restrict__ right,
    float* __restrict__ out,
    int D)
{
    // one 16B slot per (r,w): 8 bf16 channels. 3*312*16 = 14976 B.
    __shared__ __align__(16) u32x4 s4[ROWS * WW];

    const int t    = threadIdx.x;
    const int bid  = blockIdx.x;             // = bg*HBLKS + hblk
    const int hblk = bid % HBLKS;
    const int bg   = bid / HBLKS;
    const int h0   = hblk * ROWS;

    const bool active = (t < ACT);
    const int  tt = active ? t : 0;
    const int  r  = tt / W4N;                // h-row within band
    const int  w4 = tt - r * W4N;
    const int  w0 = 4 * w4;

    const size_t base   = (size_t)bg * CPG * HW + (size_t)h0 * WW;
    const size_t rowoff = base + (size_t)r * WW + w0;

    // L operands: packed bf16 pairs, pre-scaled by 1/CPG (pow2 -> exact).
    // LJP[j] = 4 pairs = 8 channels for output column w0+j.
    u32x4 LJP[4] = {{0,0,0,0},{0,0,0,0},{0,0,0,0},{0,0,0,0}};

    if (active) {
        // ---- phase 1: R -> pack -> LDS ----
        {
            f32x4 R[8];
            #pragma unroll
            for (int c = 0; c < CPG; ++c)
                R[c] = *(const f32x4*)(right + rowoff + (size_t)c * HW);

            u32x4* srow = s4 + r * WW;
            #pragma unroll
            for (int i = 0; i < 4; ++i) {
                const int s  = w0 + i;
                const int sl = s ^ ((s >> 3) & 7);
                u32x4 v;
                v.x = pkbf(R[0][i], R[1][i]);
                v.y = pkbf(R[2][i], R[3][i]);
                v.z = pkbf(R[4][i], R[5][i]);
                v.w = pkbf(R[6][i], R[7][i]);
                srow[sl] = v;
            }
        }
        // ---- phase 2: L -> scale -> pack -> LJP ----
        {
            f32x4 L[8];
            #pragma unroll
            for (int c = 0; c < CPG; ++c)
                L[c] = *(const f32x4*)(left + rowoff + (size_t)c * HW) * SCALE;
            #pragma unroll
            for (int j = 0; j < 4; ++j) {
                LJP[j].x = pkbf(L[0][j], L[1][j]);
                LJP[j].y = pkbf(L[2][j], L[3][j]);
                LJP[j].z = pkbf(L[4][j], L[5][j]);
                LJP[j].w = pkbf(L[6][j], L[7][j]);
            }
        }
    }
    __syncthreads();

    const u32x4* f4row = s4 + r * WW;

    #define RVEC(x, A) do {                          \
        int xi_ = (x) < 0 ? 0 : (x);                 \
        A = f4row[xi_ ^ ((xi_ >> 3) & 7)];           \
    } while (0)

    #define STEP(A_0, A_1, A_2, A_3) do {                    \
        f32x4 st_;                                           \
        st_.x = (x0     >= 0) ? dot8bf(A_0, LJP[0]) : 0.0f;  \
        st_.y = (x0 + 1 >= 0) ? dot8bf(A_1, LJP[1]) : 0.0f;  \
        st_.z = (x0 + 2 >= 0) ? dot8bf(A_2, LJP[2]) : 0.0f;  \
        st_.w = (x0 + 3 >= 0) ? dot8bf(A_3, LJP[3]) : 0.0f;  \
        if (active) *(f32x4*)op = st_;                       \
        op += HW;                                            \
    } while (0)

    // init window: W_j = R[w0+j] (all indices >= 0)
    u32x4 A0, A1, A2, A3;
    RVEC(w0 + 0, A0);
    RVEC(w0 + 1, A1);
    RVEC(w0 + 2, A2);
    RVEC(w0 + 3, A3);

    float* op = out + (size_t)bg * D * HW + (size_t)(h0 + r) * WW + w0;
    int x0 = w0;                       // = w0 - d

    const int nq = D >> 2;
    for (int q = 0; q < nq; ++q) {
        STEP(A0, A1, A2, A3);  RVEC(x0 - 1, A3);  x0 -= 1;
        STEP(A3, A0, A1, A2);  RVEC(x0 - 1, A2);  x0 -= 1;
        STEP(A2, A3, A0, A1);  RVEC(x0 - 1, A1);  x0 -= 1;
        STEP(A1, A2, A3, A0);  RVEC(x0 - 1, A0);  x0 -= 1;
    }

    // remainder for D % 4 != 0 (dead for D=48, kept for safety)
    for (int d = nq * 4; d < D; ++d) {
        const int xb = w0 - d;
        u32x4 Xa;
        f32x4 st_;
        RVEC(xb + 0, Xa); st_.x = (xb     >= 0) ? dot8bf(Xa, LJP[0]) : 0.0f;
        RVEC(xb + 1, Xa); st_.y = (xb + 1 >= 0) ? dot8bf(Xa, LJP[1]) : 0.0f;
        RVEC(xb + 2, Xa); st_.z = (xb + 2 >= 0) ? dot8bf(Xa, LJP[2]) : 0.0f;
        RVEC(xb + 3, Xa); st_.w = (xb + 3 >= 0) ? dot8bf(Xa, LJP[3]) : 0.0f;
        if (active) *(f32x4*)op = st_;
        op += HW;
    }

    #undef RVEC
    #undef STEP
}

extern "C" void kernel_launch(void* const* d_in, const int* in_sizes, int n_in,
                              void* d_out, int out_size, void* d_ws, size_t ws_size,
                              hipStream_t stream) {
    const float* left  = (const float*)d_in[0];
    const float* right = (const float*)d_in[1];
    float* out = (float*)d_out;

    // max_disp lives in device memory (d_in[2]); derive D from out_size on host.
    const int D = out_size / (BB * GG * HH * WW);   // = 48

    dim3 grid(BB * GG * HBLKS);   // 2560 blocks, one per (b,g,3-row band)
    dim3 block(NTH);              // 4 waves; 234 active threads
    hipLaunchKernelGGL(gwc_volume_kernel, grid, block, 0, stream,
                       left, right, out, D);
}

// Round 11
// 138.196 us; speedup vs baseline: 2.2562x; 1.0474x over previous
//
#include <hip/hip_runtime.h>

// GwcVolume: group-wise correlation cost volume.
// left/right: [B, C, H, W] fp32, C = G*CPG (320 = 40*8)
// out: [B, G, D, H, W] fp32
// out[b,g,d,h,w] = (w>=d) ? (1/CPG) * sum_ch L[b,g,ch,h,w]*R[b,g,ch,h,w-d] : 0
//
// Round 11 = R5 (best: 137.9us, absmax 0.0078) + bijective XCD chunk swizzle.
// Single-variable A/B. Mechanism: default round-robin scatters adjacent
// h-bands of one (b,g) plane across all 8 XCDs -> each XCD L2 emits
// interleaved 3.7KB chunks over the full 460MB output. Chunked swizzle
// (logical = (hw%8)*240 + hw/8; 1920%8==0 -> bijective) gives each XCD
// 10 complete (b,g) planes: contiguous 55MB write window per XCD L2 ->
// better HBM burst formation. No read-side effect (blocks share no reads).
//
// Base structure (R5, proven):
//  - block = (b,g, 4 h-rows) band, 320 thr (312 active), thread owns 4 w's.
//  - f32 LDS [r][w][ch] as f32x4 pairs, XOR swizzle (2w+half)^((w>>2)&7):
//    conflict-free b128 at lane stride 4 in w (R2: SQ_LDS_BANK_CONFLICT=0).
//  - vectorized staging: 8 R + 8 L f32x4 loads per thread, in-reg transpose,
//    8 swizzled ds_write_b128.
//  - d-loop: register sliding window (1 new R-vec = 2 b128 per d-step),
//    unrolled x4 with register rotation; f32x4 stores.
//  - __launch_bounds__(320,5): 40KB LDS -> exactly 4 blocks/CU, 20 waves.

typedef float f32x4 __attribute__((ext_vector_type(4)));

#define BB   2
#define GG   40
#define CPG  8
#define HH   96
#define WW   312
#define HW   (HH * WW)
#define ROWS 4              // h-rows per band
#define W4N  (WW / 4)       // 78 float4-groups per row
#define ACT  (ROWS * W4N)   // 312 active threads
#define NTH  320            // 5 waves
#define F4PR (2 * WW)       // 624 f32x4 slots per LDS row
#define SCALE (1.0f / CPG)
#define NWG  (BB * GG * (HH / ROWS))   // 1920 blocks
#define NXCD 8
#define CPX  (NWG / NXCD)              // 240 blocks per XCD chunk

__global__ __launch_bounds__(NTH, 5) void gwc_volume_kernel(
    const float* __restrict__ left,
    const float* __restrict__ right,
    float* __restrict__ out,
    int D)
{
    __shared__ __align__(16) f32x4 s4[ROWS * F4PR];   // 39936 B -> 4 blocks/CU

    const int t = threadIdx.x;
    // XCD chunk swizzle: hw block i runs on XCD i%8; give XCD k the
    // contiguous logical range [k*CPX, (k+1)*CPX). Bijective (1920%8==0).
    const int bid  = (blockIdx.x % NXCD) * CPX + blockIdx.x / NXCD;
    const int hblk = bid % (HH / ROWS);
    const int bg   = bid / (HH / ROWS);
    const int h0   = hblk * ROWS;

    const bool active = (t < ACT);
    const int  tt = active ? t : 0;
    const int  r  = tt / W4N;                // h-row within band
    const int  w4 = tt - r * W4N;
    const int  w0 = 4 * w4;

    // start of (bg, ch=0, h0, 0); rows h0..h0+3 contiguous per channel
    const size_t base   = (size_t)bg * CPG * HW + (size_t)h0 * WW;
    const size_t rowoff = base + (size_t)r * WW + w0;

    float LJ[4][8];          // L operands, pre-scaled by 1/CPG

    if (active) {
        // ---- issue all 16 loads (8 R + 8 L) back-to-back: full MLP ----
        f32x4 R[8], L[8];
        #pragma unroll
        for (int c = 0; c < CPG; ++c)
            R[c] = *(const f32x4*)(right + rowoff + (size_t)c * HW);
        #pragma unroll
        for (int c = 0; c < CPG; ++c)
            L[c] = *(const f32x4*)(left + rowoff + (size_t)c * HW);

        // ---- in-register transpose -> 8 swizzled ds_write_b128 ----
        // slot(w0+i, half) = (2*(w0+i) + half) ^ k,  k = w4 & 7
        const int k = w4 & 7;
        f32x4* srow = s4 + r * F4PR;
        #pragma unroll
        for (int i = 0; i < 4; ++i) {
            const int sl = (2 * (w0 + i)) ^ k;
            srow[sl]     = (f32x4){R[0][i], R[1][i], R[2][i], R[3][i]};
            srow[sl ^ 1] = (f32x4){R[4][i], R[5][i], R[6][i], R[7][i]};
        }

        #pragma unroll
        for (int c = 0; c < CPG; ++c) {
            LJ[0][c] = L[c].x * SCALE;
            LJ[1][c] = L[c].y * SCALE;
            LJ[2][c] = L[c].z * SCALE;
            LJ[3][c] = L[c].w * SCALE;
        }
    } else {
        #pragma unroll
        for (int j = 0; j < 4; ++j)
            #pragma unroll
            for (int c = 0; c < CPG; ++c)
                LJ[j][c] = 0.0f;
    }
    __syncthreads();

    const f32x4* f4row = s4 + r * F4PR;

    #define RVEC(x, A, B) do {                       \
        int xi_ = (x) < 0 ? 0 : (x);                 \
        int k_  = (xi_ >> 2) & 7;                    \
        int sl_ = (2 * xi_) ^ k_;                    \
        A = f4row[sl_];                              \
        B = f4row[sl_ ^ 1];                          \
    } while (0)

    #define DOT8(j, A, B) (LJ[j][0]*A.x + LJ[j][1]*A.y + LJ[j][2]*A.z + LJ[j][3]*A.w \
                         + LJ[j][4]*B.x + LJ[j][5]*B.y + LJ[j][6]*B.z + LJ[j][7]*B.w)

    #define STEP(A_0,B_0, A_1,B_1, A_2,B_2, A_3,B_3) do {      \
        f32x4 st_;                                             \
        st_.x = (x0     >= 0) ? DOT8(0, A_0, B_0) : 0.0f;      \
        st_.y = (x0 + 1 >= 0) ? DOT8(1, A_1, B_1) : 0.0f;      \
        st_.z = (x0 + 2 >= 0) ? DOT8(2, A_2, B_2) : 0.0f;      \
        st_.w = (x0 + 3 >= 0) ? DOT8(3, A_3, B_3) : 0.0f;      \
        if (active) *(f32x4*)op = st_;                         \
        op += HW;                                              \
    } while (0)

    // init window: V_j = R[w0+j]  (all indices >= 0)
    f32x4 A0,B0, A1,B1, A2,B2, A3,B3;
    RVEC(w0 + 0, A0, B0);
    RVEC(w0 + 1, A1, B1);
    RVEC(w0 + 2, A2, B2);
    RVEC(w0 + 3, A3, B3);

    float* op = out + (size_t)bg * D * HW + (size_t)(h0 + r) * WW + w0;
    int x0 = w0;                       // = w0 - d

    const int nq = D >> 2;
    for (int q = 0; q < nq; ++q) {
        STEP(A0,B0, A1,B1, A2,B2, A3,B3);  RVEC(x0 - 1, A3, B3);  x0 -= 1;
        STEP(A3,B3, A0,B0, A1,B1, A2,B2);  RVEC(x0 - 1, A2, B2);  x0 -= 1;
        STEP(A2,B2, A3,B3, A0,B0, A1,B1);  RVEC(x0 - 1, A1, B1);  x0 -= 1;
        STEP(A1,B1, A2,B2, A3,B3, A0,B0);  RVEC(x0 - 1, A0, B0);  x0 -= 1;
    }

    // remainder for D % 4 != 0 (dead for D=48, kept for safety)
    for (int d = nq * 4; d < D; ++d) {
        const int xb = w0 - d;
        f32x4 Xa, Xb, st_;
        RVEC(xb + 0, Xa, Xb); st_.x = (xb     >= 0) ? DOT8(0, Xa, Xb) : 0.0f;
        RVEC(xb + 1, Xa, Xb); st_.y = (xb + 1 >= 0) ? DOT8(1, Xa, Xb) : 0.0f;
        RVEC(xb + 2, Xa, Xb); st_.z = (xb + 2 >= 0) ? DOT8(2, Xa, Xb) : 0.0f;
        RVEC(xb + 3, Xa, Xb); st_.w = (xb + 3 >= 0) ? DOT8(3, Xa, Xb) : 0.0f;
        if (active) *(f32x4*)op = st_;
        op += HW;
    }

    #undef RVEC
    #undef DOT8
    #undef STEP
}

extern "C" void kernel_launch(void* const* d_in, const int* in_sizes, int n_in,
                              void* d_out, int out_size, void* d_ws, size_t ws_size,
                              hipStream_t stream) {
    const float* left  = (const float*)d_in[0];
    const float* right = (const float*)d_in[1];
    float* out = (float*)d_out;

    // max_disp lives in device memory (d_in[2]); derive D from out_size on host.
    const int D = out_size / (BB * GG * HH * WW);   // = 48

    dim3 grid(NWG);    // 1920 blocks, one per (b,g,4-row band)
    dim3 block(NTH);   // 5 waves; 312 active threads
    hipLaunchKernelGGL(gwc_volume_kernel, grid, block, 0, stream,
                       left, right, out, D);
}

// Round 12
// 134.855 us; speedup vs baseline: 2.3121x; 1.0248x over previous
//
#include <hip/hip_runtime.h>

// GwcVolume: group-wise correlation cost volume.
// left/right: [B, C, H, W] fp32, C = G*CPG (320 = 40*8)
// out: [B, G, D, H, W] fp32
// out[b,g,d,h,w] = (w>=d) ? (1/CPG) * sum_ch L[b,g,ch,h,w]*R[b,g,ch,h,w-d] : 0
//
// Round 12 = R10 (dot2/bf16) with ROWS=8, 640 threads.
// Rationale: all structural variants converge ~138-147us = 4.4 TB/s while
// copy(1:1)=6.3 and fill(0:1)=6.8 TB/s on this chip -> not a bus limit.
// Suspect: small scattered write chunks (4992B per block,d then 117KB jump).
// ROWS=8 doubles the contiguous chunk to 9984B; h-rows are memory-adjacent so
// even row-straddling waves issue ONE contiguous 1024B store run.
// Also fixes the hidden ROWS=3 lane waste (624/640=97.5% vs 234/256=91.4%)
// and halves grid to 960 (staging overhead halves). dot2-packed live set ~50
// VGPR -> possibly 3 blocks x 10 waves = 30 waves/CU (no launch_bounds; caps
// proven to spill in R6-R8).
//  - bf16 LDS [r][w][8ch] 16B slots (39936 B), swizzle s^((s>>3)&7);
//    row stride 1248 words %32==0 -> straddle reads <=2-way conflict (free).
//  - ONE ds_read_b128 per d-step; sliding window unrolled x4 w/ rotation.
//  - DOT8 = 4 chained v_dot2_f32_bf16; L pre-scaled by 1/8 (pow2, exact),
//    packed bf16 (16 VGPR).

typedef float f32x4 __attribute__((ext_vector_type(4)));
typedef unsigned int u32;
typedef u32 u32x4 __attribute__((ext_vector_type(4)));

#define BB   2
#define GG   40
#define CPG  8
#define HH   96
#define WW   312
#define HW   (HH * WW)
#define ROWS 8              // h-rows per band
#define W4N  (WW / 4)       // 78 w-groups per row
#define ACT  (ROWS * W4N)   // 624 active threads
#define NTH  640            // 10 waves
#define HBLKS (HH / ROWS)   // 12 bands per (b,g)
#define SCALE (1.0f / CPG)

// pack two f32 -> (bf16_rne(a) | bf16_rne(b)<<16)
__device__ __forceinline__ u32 pkbf(float a, float b) {
    u32 ua = __builtin_bit_cast(u32, a);
    u32 ub = __builtin_bit_cast(u32, b);
    ua += 0x7fffu + ((ua >> 16) & 1u);
    ub += 0x7fffu + ((ub >> 16) & 1u);
    return (ua >> 16) | (ub & 0xffff0000u);
}

// D = a.lo*b.lo + a.hi*b.hi + c   (packed bf16 pair dot, f32 accum)
__device__ __forceinline__ float dot2bf(u32 a, u32 b, float c) {
    float d;
    asm("v_dot2_f32_bf16 %0, %1, %2, %3" : "=v"(d) : "v"(a), "v"(b), "v"(c));
    return d;
}

// 8-channel dot: a,b = 4 packed pairs each
__device__ __forceinline__ float dot8bf(u32x4 a, u32x4 b) {
    float acc = dot2bf(a.x, b.x, 0.0f);
    acc = dot2bf(a.y, b.y, acc);
    acc = dot2bf(a.z, b.z, acc);
    acc = dot2bf(a.w, b.w, acc);
    return acc;
}

__global__ void gwc_volume_kernel(
    const float* __restrict__ left,
    const float* __restrict__ right,
    float* __restrict__ out,
    int D)
{
    // one 16B slot per (r,w): 8 bf16 channels. 8*312*16 = 39936 B.
    __shared__ __align__(16) u32x4 s4[ROWS * WW];

    const int t    = threadIdx.x;
    const int bid  = blockIdx.x;             // = bg*HBLKS + hblk
    const int hblk = bid % HBLKS;
    const int bg   = bid / HBLKS;
    const int h0   = hblk * ROWS;

    const bool active = (t < ACT);
    const int  tt = active ? t : 0;
    const int  r  = tt / W4N;                // h-row within band
    const int  w4 = tt - r * W4N;
    const int  w0 = 4 * w4;

    const size_t base   = (size_t)bg * CPG * HW + (size_t)h0 * WW;
    const size_t rowoff = base + (size_t)r * WW + w0;

    // L operands: packed bf16 pairs, pre-scaled by 1/CPG (pow2 -> exact).
    u32x4 LJP[4] = {{0,0,0,0},{0,0,0,0},{0,0,0,0},{0,0,0,0}};

    if (active) {
        // ---- phase 1: R -> pack -> LDS ----
        {
            f32x4 R[8];
            #pragma unroll
            for (int c = 0; c < CPG; ++c)
                R[c] = *(const f32x4*)(right + rowoff + (size_t)c * HW);

            u32x4* srow = s4 + r * WW;
            #pragma unroll
            for (int i = 0; i < 4; ++i) {
                const int s  = w0 + i;
                const int sl = s ^ ((s >> 3) & 7);
                u32x4 v;
                v.x = pkbf(R[0][i], R[1][i]);
                v.y = pkbf(R[2][i], R[3][i]);
                v.z = pkbf(R[4][i], R[5][i]);
                v.w = pkbf(R[6][i], R[7][i]);
                srow[sl] = v;
            }
        }
        // ---- phase 2: L -> scale -> pack -> LJP ----
        {
            f32x4 L[8];
            #pragma unroll
            for (int c = 0; c < CPG; ++c)
                L[c] = *(const f32x4*)(left + rowoff + (size_t)c * HW) * SCALE;
            #pragma unroll
            for (int j = 0; j < 4; ++j) {
                LJP[j].x = pkbf(L[0][j], L[1][j]);
                LJP[j].y = pkbf(L[2][j], L[3][j]);
                LJP[j].z = pkbf(L[4][j], L[5][j]);
                LJP[j].w = pkbf(L[6][j], L[7][j]);
            }
        }
    }
    __syncthreads();

    const u32x4* f4row = s4 + r * WW;

    #define RVEC(x, A) do {                          \
        int xi_ = (x) < 0 ? 0 : (x);                 \
        A = f4row[xi_ ^ ((xi_ >> 3) & 7)];           \
    } while (0)

    #define STEP(A_0, A_1, A_2, A_3) do {                    \
        f32x4 st_;                                           \
        st_.x = (x0     >= 0) ? dot8bf(A_0, LJP[0]) : 0.0f;  \
        st_.y = (x0 + 1 >= 0) ? dot8bf(A_1, LJP[1]) : 0.0f;  \
        st_.z = (x0 + 2 >= 0) ? dot8bf(A_2, LJP[2]) : 0.0f;  \
        st_.w = (x0 + 3 >= 0) ? dot8bf(A_3, LJP[3]) : 0.0f;  \
        if (active) *(f32x4*)op = st_;                       \
        op += HW;                                            \
    } while (0)

    // init window: W_j = R[w0+j] (all indices >= 0)
    u32x4 A0, A1, A2, A3;
    RVEC(w0 + 0, A0);
    RVEC(w0 + 1, A1);
    RVEC(w0 + 2, A2);
    RVEC(w0 + 3, A3);

    float* op = out + (size_t)bg * D * HW + (size_t)(h0 + r) * WW + w0;
    int x0 = w0;                       // = w0 - d

    const int nq = D >> 2;
    for (int q = 0; q < nq; ++q) {
        STEP(A0, A1, A2, A3);  RVEC(x0 - 1, A3);  x0 -= 1;
        STEP(A3, A0, A1, A2);  RVEC(x0 - 1, A2);  x0 -= 1;
        STEP(A2, A3, A0, A1);  RVEC(x0 - 1, A1);  x0 -= 1;
        STEP(A1, A2, A3, A0);  RVEC(x0 - 1, A0);  x0 -= 1;
    }

    // remainder for D % 4 != 0 (dead for D=48, kept for safety)
    for (int d = nq * 4; d < D; ++d) {
        const int xb = w0 - d;
        u32x4 Xa;
        f32x4 st_;
        RVEC(xb + 0, Xa); st_.x = (xb     >= 0) ? dot8bf(Xa, LJP[0]) : 0.0f;
        RVEC(xb + 1, Xa); st_.y = (xb + 1 >= 0) ? dot8bf(Xa, LJP[1]) : 0.0f;
        RVEC(xb + 2, Xa); st_.z = (xb + 2 >= 0) ? dot8bf(Xa, LJP[2]) : 0.0f;
        RVEC(xb + 3, Xa); st_.w = (xb + 3 >= 0) ? dot8bf(Xa, LJP[3]) : 0.0f;
        if (active) *(f32x4*)op = st_;
        op += HW;
    }

    #undef RVEC
    #undef STEP
}

extern "C" void kernel_launch(void* const* d_in, const int* in_sizes, int n_in,
                              void* d_out, int out_size, void* d_ws, size_t ws_size,
                              hipStream_t stream) {
    const float* left  = (const float*)d_in[0];
    const float* right = (const float*)d_in[1];
    float* out = (float*)d_out;

    // max_disp lives in device memory (d_in[2]); derive D from out_size on host.
    const int D = out_size / (BB * GG * HH * WW);   // = 48

    dim3 grid(BB * GG * HBLKS);   // 960 blocks, one per (b,g,8-row band)
    dim3 block(NTH);              // 10 waves; 624 active threads
    hipLaunchKernelGGL(gwc_volume_kernel, grid, block, 0, stream,
                       left, right, out, D);
}

// Round 13
// 102.326 us; speedup vs baseline: 3.0471x; 1.3179x over previous
//
#include <hip/hip_runtime.h>

// GwcVolume: group-wise correlation cost volume.
// left/right: [B, C, H, W] fp32, C = G*CPG (320 = 40*8)
// out: [B, G, D, H, W] fp32
// out[b,g,d,h,w] = (w>=d) ? (1/CPG) * sum_ch L[b,g,ch,h,w]*R[b,g,ch,h,w-d] : 0
//
// Round 13 = R12 (best, 134.9us) + NONTEMPORAL STORES ONLY (isolated A/B).
// Mechanism under test: 460MB output streaming through 32MB aggregate L2 with
// write-allocate -> constant dirty-line alloc/evict competing with read fills.
// nt stores let the write stream drain without L2 allocation. (R4 bundled
// nt-loads+nt-stores with an occupancy cliff -> never isolated.) Loads stay
// default. Everything else byte-identical to R12:
//  - block = (bg, 8 h-rows), 640 thr (624 active), grid 960.
//  - bf16 LDS [r][w][8ch] 16B slots (39936 B), swizzle s^((s>>3)&7).
//  - ONE ds_read_b128 per d-step; sliding window unrolled x4 w/ rotation.
//  - DOT8 = 4 chained v_dot2_f32_bf16; L pre-scaled 1/8 (exact), packed bf16.
//  - no launch_bounds (caps spill: R6-R8).

typedef float f32x4 __attribute__((ext_vector_type(4)));
typedef unsigned int u32;
typedef u32 u32x4 __attribute__((ext_vector_type(4)));

#define BB   2
#define GG   40
#define CPG  8
#define HH   96
#define WW   312
#define HW   (HH * WW)
#define ROWS 8              // h-rows per band
#define W4N  (WW / 4)       // 78 w-groups per row
#define ACT  (ROWS * W4N)   // 624 active threads
#define NTH  640            // 10 waves
#define HBLKS (HH / ROWS)   // 12 bands per (b,g)
#define SCALE (1.0f / CPG)

// pack two f32 -> (bf16_rne(a) | bf16_rne(b)<<16)
__device__ __forceinline__ u32 pkbf(float a, float b) {
    u32 ua = __builtin_bit_cast(u32, a);
    u32 ub = __builtin_bit_cast(u32, b);
    ua += 0x7fffu + ((ua >> 16) & 1u);
    ub += 0x7fffu + ((ub >> 16) & 1u);
    return (ua >> 16) | (ub & 0xffff0000u);
}

// D = a.lo*b.lo + a.hi*b.hi + c   (packed bf16 pair dot, f32 accum)
__device__ __forceinline__ float dot2bf(u32 a, u32 b, float c) {
    float d;
    asm("v_dot2_f32_bf16 %0, %1, %2, %3" : "=v"(d) : "v"(a), "v"(b), "v"(c));
    return d;
}

// 8-channel dot: a,b = 4 packed pairs each
__device__ __forceinline__ float dot8bf(u32x4 a, u32x4 b) {
    float acc = dot2bf(a.x, b.x, 0.0f);
    acc = dot2bf(a.y, b.y, acc);
    acc = dot2bf(a.z, b.z, acc);
    acc = dot2bf(a.w, b.w, acc);
    return acc;
}

__global__ void gwc_volume_kernel(
    const float* __restrict__ left,
    const float* __restrict__ right,
    float* __restrict__ out,
    int D)
{
    // one 16B slot per (r,w): 8 bf16 channels. 8*312*16 = 39936 B.
    __shared__ __align__(16) u32x4 s4[ROWS * WW];

    const int t    = threadIdx.x;
    const int bid  = blockIdx.x;             // = bg*HBLKS + hblk
    const int hblk = bid % HBLKS;
    const int bg   = bid / HBLKS;
    const int h0   = hblk * ROWS;

    const bool active = (t < ACT);
    const int  tt = active ? t : 0;
    const int  r  = tt / W4N;                // h-row within band
    const int  w4 = tt - r * W4N;
    const int  w0 = 4 * w4;

    const size_t base   = (size_t)bg * CPG * HW + (size_t)h0 * WW;
    const size_t rowoff = base + (size_t)r * WW + w0;

    // L operands: packed bf16 pairs, pre-scaled by 1/CPG (pow2 -> exact).
    u32x4 LJP[4] = {{0,0,0,0},{0,0,0,0},{0,0,0,0},{0,0,0,0}};

    if (active) {
        // ---- phase 1: R -> pack -> LDS ----
        {
            f32x4 R[8];
            #pragma unroll
            for (int c = 0; c < CPG; ++c)
                R[c] = *(const f32x4*)(right + rowoff + (size_t)c * HW);

            u32x4* srow = s4 + r * WW;
            #pragma unroll
            for (int i = 0; i < 4; ++i) {
                const int s  = w0 + i;
                const int sl = s ^ ((s >> 3) & 7);
                u32x4 v;
                v.x = pkbf(R[0][i], R[1][i]);
                v.y = pkbf(R[2][i], R[3][i]);
                v.z = pkbf(R[4][i], R[5][i]);
                v.w = pkbf(R[6][i], R[7][i]);
                srow[sl] = v;
            }
        }
        // ---- phase 2: L -> scale -> pack -> LJP ----
        {
            f32x4 L[8];
            #pragma unroll
            for (int c = 0; c < CPG; ++c)
                L[c] = *(const f32x4*)(left + rowoff + (size_t)c * HW) * SCALE;
            #pragma unroll
            for (int j = 0; j < 4; ++j) {
                LJP[j].x = pkbf(L[0][j], L[1][j]);
                LJP[j].y = pkbf(L[2][j], L[3][j]);
                LJP[j].z = pkbf(L[4][j], L[5][j]);
                LJP[j].w = pkbf(L[6][j], L[7][j]);
            }
        }
    }
    __syncthreads();

    const u32x4* f4row = s4 + r * WW;

    #define RVEC(x, A) do {                          \
        int xi_ = (x) < 0 ? 0 : (x);                 \
        A = f4row[xi_ ^ ((xi_ >> 3) & 7)];           \
    } while (0)

    #define STEP(A_0, A_1, A_2, A_3) do {                    \
        f32x4 st_;                                           \
        st_.x = (x0     >= 0) ? dot8bf(A_0, LJP[0]) : 0.0f;  \
        st_.y = (x0 + 1 >= 0) ? dot8bf(A_1, LJP[1]) : 0.0f;  \
        st_.z = (x0 + 2 >= 0) ? dot8bf(A_2, LJP[2]) : 0.0f;  \
        st_.w = (x0 + 3 >= 0) ? dot8bf(A_3, LJP[3]) : 0.0f;  \
        if (active) __builtin_nontemporal_store(st_, (f32x4*)op); \
        op += HW;                                            \
    } while (0)

    // init window: W_j = R[w0+j] (all indices >= 0)
    u32x4 A0, A1, A2, A3;
    RVEC(w0 + 0, A0);
    RVEC(w0 + 1, A1);
    RVEC(w0 + 2, A2);
    RVEC(w0 + 3, A3);

    float* op = out + (size_t)bg * D * HW + (size_t)(h0 + r) * WW + w0;
    int x0 = w0;                       // = w0 - d

    const int nq = D >> 2;
    for (int q = 0; q < nq; ++q) {
        STEP(A0, A1, A2, A3);  RVEC(x0 - 1, A3);  x0 -= 1;
        STEP(A3, A0, A1, A2);  RVEC(x0 - 1, A2);  x0 -= 1;
        STEP(A2, A3, A0, A1);  RVEC(x0 - 1, A1);  x0 -= 1;
        STEP(A1, A2, A3, A0);  RVEC(x0 - 1, A0);  x0 -= 1;
    }

    // remainder for D % 4 != 0 (dead for D=48, kept for safety)
    for (int d = nq * 4; d < D; ++d) {
        const int xb = w0 - d;
        u32x4 Xa;
        f32x4 st_;
        RVEC(xb + 0, Xa); st_.x = (xb     >= 0) ? dot8bf(Xa, LJP[0]) : 0.0f;
        RVEC(xb + 1, Xa); st_.y = (xb + 1 >= 0) ? dot8bf(Xa, LJP[1]) : 0.0f;
        RVEC(xb + 2, Xa); st_.z = (xb + 2 >= 0) ? dot8bf(Xa, LJP[2]) : 0.0f;
        RVEC(xb + 3, Xa); st_.w = (xb + 3 >= 0) ? dot8bf(Xa, LJP[3]) : 0.0f;
        if (active) __builtin_nontemporal_store(st_, (f32x4*)op);
        op += HW;
    }

    #undef RVEC
    #undef STEP
}

extern "C" void kernel_launch(void* const* d_in, const int* in_sizes, int n_in,
                              void* d_out, int out_size, void* d_ws, size_t ws_size,
                              hipStream_t stream) {
    const float* left  = (const float*)d_in[0];
    const float* right = (const float*)d_in[1];
    float* out = (float*)d_out;

    // max_disp lives in device memory (d_in[2]); derive D from out_size on host.
    const int D = out_size / (BB * GG * HH * WW);   // = 48

    dim3 grid(BB * GG * HBLKS);   // 960 blocks, one per (b,g,8-row band)
    dim3 block(NTH);              // 10 waves; 624 active threads
    hipLaunchKernelGGL(gwc_volume_kernel, grid, block, 0, stream,
                       left, right, out, D);
}